// Round 1
// baseline (315.582 us; speedup 1.0000x reference)
//
#include <hip/hip_runtime.h>
#include <stdint.h>

#define HID 64
#define TT  512
#define BT  16   // batch tile per workgroup
#define XS_STRIDE 516  // 512 + 4 pad: breaks bank aliasing on per-step x reads

typedef float  f32x4  __attribute__((ext_vector_type(4)));
typedef short  s16x8  __attribute__((ext_vector_type(8)));
typedef __bf16 bf16x8 __attribute__((ext_vector_type(8)));

#define MFMA_BF16(A, B, C) \
    __builtin_amdgcn_mfma_f32_16x16x32_bf16( \
        __builtin_bit_cast(bf16x8, (A)), __builtin_bit_cast(bf16x8, (B)), (C), 0, 0, 0)

__device__ __forceinline__ float fast_sigmoid(float a) {
    float e = __builtin_amdgcn_exp2f(a * -1.44269504088896f);
    return __builtin_amdgcn_rcpf(1.0f + e);
}
__device__ __forceinline__ float fast_tanh(float a) {
    float e = __builtin_amdgcn_exp2f(a * 2.88539008177793f);
    return 1.0f - 2.0f * __builtin_amdgcn_rcpf(e + 1.0f);
}

__device__ __forceinline__ unsigned short bf16_trunc_bits(float v) {
    union { float f; unsigned u; } x; x.f = v;
    return (unsigned short)(x.u >> 16);
}
__device__ __forceinline__ float bf16_hi_f32(float v) {
    union { float f; unsigned u; } x; x.f = v;
    x.u &= 0xffff0000u;
    return x.f;
}
__device__ __forceinline__ unsigned short bf16_rne_bits(float v) {
    union { float f; unsigned u; } x; x.f = v;
    unsigned r = x.u + 0x7fffu + ((x.u >> 16) & 1u);
    return (unsigned short)(r >> 16);
}

// One workgroup = 16 batches, 4 waves. Wave w owns hidden slice q in [16w,16w+16).
// Each wave holds W_hh B-fragments (3 gates x 2 K-chunks, hi+lo bf16) in registers.
// h round-trips through LDS in A-fragment order each step (double-buffered).
__global__ __launch_bounds__(256) void gru_scan_kernel(
    const float* __restrict__ x,     // (4096, 512, 1)
    const float* __restrict__ Wih,   // (192, 1)
    const float* __restrict__ Whh,   // (192, 64)
    const float* __restrict__ bih,   // (192)
    const float* __restrict__ bhh,   // (192)
    const float* __restrict__ Wout,  // (1, 64)
    const float* __restrict__ bout,  // (1)
    float* __restrict__ out)         // (4096, 1)
{
    __shared__ __align__(16) float xs[BT * XS_STRIDE];
    // [dbuf][hi/lo][chunk][slot 0..63][8 bf16 bits] : A-fragment order
    __shared__ __align__(16) short hbuf[2][2][2][64][8];
    __shared__ float outp[4][BT];

    const int tid  = threadIdx.x;
    const int w    = tid >> 6;        // wave id 0..3
    const int L    = tid & 63;        // lane
    const int n16  = L & 15;
    const int quad = L >> 4;
    const int q    = w * 16 + n16;    // this lane's hidden unit (D-layout col)
    const int b0   = blockIdx.x * BT;

    // ---- stage x tile (16 rows x 512) into LDS, coalesced ----
    {
        const int m    = tid >> 4;
        const int part = tid & 15;
        const f32x4* gx = (const f32x4*)(x + (size_t)(b0 + m) * TT);
        f32x4*       lx = (f32x4*)(xs + m * XS_STRIDE);
        #pragma unroll
        for (int k2 = 0; k2 < 8; ++k2) {
            int t4 = part + k2 * 16;
            lx[t4] = gx[t4];
        }
    }
    // ---- zero both h double-buffers (h0 = 0) ----
    {
        f32x4* hb = (f32x4*)&hbuf[0][0][0][0][0];  // 8192 B = 512 f32x4
        f32x4 zv = {0.f, 0.f, 0.f, 0.f};
        hb[tid]       = zv;
        hb[tid + 256] = zv;
    }

    // ---- per-lane constants ----
    const float wr    = Wih[q];
    const float wz    = Wih[64 + q];
    const float wn    = Wih[128 + q];
    const float biasR = bih[q]      + bhh[q];
    const float biasZ = bih[64 + q] + bhh[64 + q];
    const float bihn  = bih[128 + q];
    const float bhn   = bhh[128 + q];
    const float wo    = Wout[q];

    // ---- W_hh B-fragments in registers: B[k][n]=Whh[n_glob][k], split hi/lo bf16 ----
    s16x8 Bhi[3][2], Blo[3][2];
    #pragma unroll
    for (int g = 0; g < 3; ++g) {
        #pragma unroll
        for (int c = 0; c < 2; ++c) {
            const float* p = Whh + ((g * 64 + q) * 64 + c * 32 + quad * 8);
            #pragma unroll
            for (int j = 0; j < 8; ++j) {
                float v   = p[j];
                float hif = bf16_hi_f32(v);
                Bhi[g][c][j] = (short)bf16_trunc_bits(v);
                Blo[g][c][j] = (short)bf16_rne_bits(v - hif);
            }
        }
    }

    // persistent h (fp32) in D-layout: reg -> (m = quad*4+reg, col q)
    float hD[4] = {0.f, 0.f, 0.f, 0.f};
    const int mbase = quad * 4;

    // writer-side A-layout address pieces for this lane's column q
    const int cw = q >> 5;          // K-chunk
    const int qd = (q & 31) >> 3;   // which 8-wide k-group
    const int jw = q & 7;           // element within group

    const s16x8* hbv = (const s16x8*)hbuf;  // frag(d,hl,c,slot) = d*256 + hl*128 + c*64 + slot

    int cur = 0;
    for (int t = 0; t < TT; ++t) {
        __syncthreads();  // step t-1 writes visible; prev-buffer reads done

        s16x8 Ahi0 = hbv[cur * 256 +   0 + L];
        s16x8 Ahi1 = hbv[cur * 256 +  64 + L];
        s16x8 Alo0 = hbv[cur * 256 + 128 + L];
        s16x8 Alo1 = hbv[cur * 256 + 192 + L];

        f32x4 aR = {biasR, biasR, biasR, biasR};
        f32x4 aZ = {biasZ, biasZ, biasZ, biasZ};
        f32x4 aN = {bhn, bhn, bhn, bhn};

        // r gate
        aR = MFMA_BF16(Ahi0, Bhi[0][0], aR);
        aR = MFMA_BF16(Ahi1, Bhi[0][1], aR);
        aR = MFMA_BF16(Ahi0, Blo[0][0], aR);
        aR = MFMA_BF16(Ahi1, Blo[0][1], aR);
        aR = MFMA_BF16(Alo0, Bhi[0][0], aR);
        aR = MFMA_BF16(Alo1, Bhi[0][1], aR);
        // z gate
        aZ = MFMA_BF16(Ahi0, Bhi[1][0], aZ);
        aZ = MFMA_BF16(Ahi1, Bhi[1][1], aZ);
        aZ = MFMA_BF16(Ahi0, Blo[1][0], aZ);
        aZ = MFMA_BF16(Ahi1, Blo[1][1], aZ);
        aZ = MFMA_BF16(Alo0, Bhi[1][0], aZ);
        aZ = MFMA_BF16(Alo1, Bhi[1][1], aZ);
        // n gate (h-part)
        aN = MFMA_BF16(Ahi0, Bhi[2][0], aN);
        aN = MFMA_BF16(Ahi1, Bhi[2][1], aN);
        aN = MFMA_BF16(Ahi0, Blo[2][0], aN);
        aN = MFMA_BF16(Ahi1, Blo[2][1], aN);
        aN = MFMA_BF16(Alo0, Bhi[2][0], aN);
        aN = MFMA_BF16(Alo1, Bhi[2][1], aN);

        const int nxt = cur ^ 1;
        short* whi = (short*)hbuf + nxt * 2048 + cw * 512 + 128 * qd + jw;
        short* wlo = whi + 1024;

        #pragma unroll
        for (int reg = 0; reg < 4; ++reg) {
            const int m = mbase + reg;
            float xv = xs[m * XS_STRIDE + t];
            float ar = __builtin_fmaf(xv, wr, aR[reg]);
            float az = __builtin_fmaf(xv, wz, aZ[reg]);
            float r  = fast_sigmoid(ar);
            float z  = fast_sigmoid(az);
            float an = __builtin_fmaf(xv, wn, bihn) + r * aN[reg];
            float n  = fast_tanh(an);
            float h  = hD[reg];
            h = __builtin_fmaf(z, h - n, n);   // (1-z)*n + z*h
            hD[reg] = h;
            float hif = bf16_hi_f32(h);
            whi[m * 8] = (short)bf16_trunc_bits(h);
            wlo[m * 8] = (short)bf16_rne_bits(h - hif);
        }
        cur = nxt;
    }

    // ---- epilogue: out[b] = sum_q h[b][q]*Wout[q] + bout ----
    float p[4];
    #pragma unroll
    for (int reg = 0; reg < 4; ++reg) p[reg] = hD[reg] * wo;
    #pragma unroll
    for (int mask = 1; mask <= 8; mask <<= 1) {
        #pragma unroll
        for (int reg = 0; reg < 4; ++reg)
            p[reg] += __shfl_xor(p[reg], mask, 64);
    }
    if (n16 == 0) {
        #pragma unroll
        for (int reg = 0; reg < 4; ++reg) outp[w][mbase + reg] = p[reg];
    }
    __syncthreads();
    if (tid < BT) {
        out[b0 + tid] = outp[0][tid] + outp[1][tid] + outp[2][tid] + outp[3][tid] + bout[0];
    }
}

extern "C" void kernel_launch(void* const* d_in, const int* in_sizes, int n_in,
                              void* d_out, int out_size, void* d_ws, size_t ws_size,
                              hipStream_t stream) {
    (void)in_sizes; (void)n_in; (void)d_ws; (void)ws_size; (void)out_size;
    const float* x    = (const float*)d_in[0];
    const float* Wih  = (const float*)d_in[1];
    const float* Whh  = (const float*)d_in[2];
    const float* bih  = (const float*)d_in[3];
    const float* bhh  = (const float*)d_in[4];
    const float* Wout = (const float*)d_in[5];
    const float* bout = (const float*)d_in[6];
    float* out = (float*)d_out;

    gru_scan_kernel<<<dim3(4096 / BT), dim3(256), 0, stream>>>(
        x, Wih, Whh, bih, bhh, Wout, bout, out);
}